// Round 1
// baseline (125.317 us; speedup 1.0000x reference)
//
#include <hip/hip_runtime.h>
#include <hip/hip_bf16.h>

#define M_TOK 2048
#define KDIM  4096
#define NDIM  4096

typedef __bf16 bf16x8 __attribute__((ext_vector_type(8)));
typedef float  f32x4  __attribute__((ext_vector_type(4)));
typedef short  short8 __attribute__((ext_vector_type(8)));

__device__ __forceinline__ ushort f2bf(float f) {
    union { float f; unsigned u; } v; v.f = f;
    unsigned r = (v.u + 0x7fffu + ((v.u >> 16) & 1u)) >> 16;
    return (ushort)r;
}

__device__ __forceinline__ void gload16(const ushort* g, ushort* l) {
    __builtin_amdgcn_global_load_lds(
        (const __attribute__((address_space(1))) void*)g,
        (__attribute__((address_space(3))) void*)l, 16, 0, 0);
}

// ---------------- kernel 1: cast x (fp32) -> bf16 ----------------
__global__ __launch_bounds__(256) void k_cast(const float* __restrict__ x,
                                              ushort* __restrict__ xb) {
    const int i = (blockIdx.x * 256 + threadIdx.x) * 8;
    float4 a = *reinterpret_cast<const float4*>(x + i);
    float4 b = *reinterpret_cast<const float4*>(x + i + 4);
    short8 o;
    o[0] = (short)f2bf(a.x); o[1] = (short)f2bf(a.y);
    o[2] = (short)f2bf(a.z); o[3] = (short)f2bf(a.w);
    o[4] = (short)f2bf(b.x); o[5] = (short)f2bf(b.y);
    o[6] = (short)f2bf(b.z); o[7] = (short)f2bf(b.w);
    *reinterpret_cast<short8*>(xb + i) = o;
}

// ---------------- kernel 2: build fused weight W3 (bf16, N x K) ----------------
// W3[o, input_perm[jp]] = alpha * pds[op] * sum_r G0[i0,j0,r] * G1[r,i1,j1]
// op = output_inv_perm[o]; i0=op>>6; i1=op&63; j0=jp>>6; j1=jp&63
__global__ __launch_bounds__(256) void k_w3(const float* __restrict__ g0,
                                            const float* __restrict__ g1,
                                            const float* __restrict__ alpha,
                                            const float* __restrict__ pds,
                                            const int* __restrict__ iperm,
                                            const int* __restrict__ oinv,
                                            ushort* __restrict__ W3) {
    __shared__ float  G0s[1024];   // [j0][r]
    __shared__ float  G1s[1024];   // [r][j1]
    __shared__ ushort rowb[4096];
    const int o  = blockIdx.x;
    const int op = oinv[o];
    const int i0 = op >> 6, i1 = op & 63;
    const float sc = alpha[0] * pds[op];

    for (int idx = threadIdx.x; idx < 1024; idx += 256) {
        G0s[idx] = g0[i0 * 1024 + idx];                             // j0*16 + r
        G1s[idx] = g1[(idx >> 6) * 4096 + i1 * 64 + (idx & 63)];    // r*64 + j1
    }
    __syncthreads();
    for (int jp = threadIdx.x; jp < 4096; jp += 256) {
        const int j0 = jp >> 6, j1 = jp & 63;
        float v = 0.f;
#pragma unroll
        for (int r = 0; r < 16; ++r)
            v = fmaf(G0s[j0 * 16 + r], G1s[r * 64 + j1], v);
        rowb[iperm[jp]] = f2bf(v * sc);
    }
    __syncthreads();
    for (int t = threadIdx.x; t < 512; t += 256)
        *reinterpret_cast<short8*>(W3 + (size_t)o * 4096 + t * 8) =
            *reinterpret_cast<const short8*>(rowb + t * 8);
}

// ---------------- kernel 3: C = A @ B^T + bias  (bf16 MFMA, fp32 out) ----------------
// A: M_TOK x KDIM bf16, B: NDIM x KDIM bf16 (row-major, contract over K)
__global__ __launch_bounds__(256, 3)
void k_gemm(const ushort* __restrict__ A, const ushort* __restrict__ B,
            const float* __restrict__ bias, float* __restrict__ C) {
    __shared__ ushort As[128 * 32];
    __shared__ ushort Bs[128 * 32];
    const int tid  = threadIdx.x;
    const int lane = tid & 63;
    const int wave = tid >> 6;

    // XCD-aware bijective swizzle (nwg = 512, divisible by 8)
    const int nbx = NDIM / 128;               // 32
    const int cpx = (M_TOK / 128) * nbx / 8;  // 64
    const int bid = blockIdx.x;
    const int swz = (bid & 7) * cpx + (bid >> 3);
    const int by = swz / nbx, bx = swz % nbx;
    const long brow = (long)by * 128, bcol = (long)bx * 128;

    const int wr = wave >> 1, wc = wave & 1;  // 2x2 waves of 64x64

    f32x4 acc[4][4] = {};

    // staging decomposition: flat = it*256 + tid; row = flat>>2; col8 = (flat&3)*8
    const int r0 = tid >> 2,        c0 = (tid & 3) << 3;
    const int r1 = (256 + tid) >> 2, c1 = (tid & 3) << 3;  // (256+tid)&3 == tid&3
    // wave-uniform LDS bases: byte offset flat_base*16 -> ushort offset flat_base*8
    ushort* ldsA0 = As + (size_t)(tid & ~63) * 8;
    ushort* ldsA1 = As + (size_t)(256 + (tid & ~63)) * 8;
    ushort* ldsB0 = Bs + (size_t)(tid & ~63) * 8;
    ushort* ldsB1 = Bs + (size_t)(256 + (tid & ~63)) * 8;

    const ushort* gA = A + brow * KDIM;
    const ushort* gB = B + bcol * KDIM;

    const int lr = lane & 15;
    const int lk = (lane >> 4) << 3;
    const ushort* pa = As + (wr * 64 + lr) * 32 + lk;
    const ushort* pb = Bs + (wc * 64 + lr) * 32 + lk;

    for (int kt = 0; kt < KDIM; kt += 32) {
        gload16(gA + (size_t)r0 * KDIM + kt + c0, ldsA0);
        gload16(gA + (size_t)r1 * KDIM + kt + c1, ldsA1);
        gload16(gB + (size_t)r0 * KDIM + kt + c0, ldsB0);
        gload16(gB + (size_t)r1 * KDIM + kt + c1, ldsB1);
        __syncthreads();

        bf16x8 af[4], bfr[4];
#pragma unroll
        for (int m = 0; m < 4; ++m)
            af[m] = *reinterpret_cast<const bf16x8*>(pa + m * 16 * 32);
#pragma unroll
        for (int n = 0; n < 4; ++n)
            bfr[n] = *reinterpret_cast<const bf16x8*>(pb + n * 16 * 32);
#pragma unroll
        for (int m = 0; m < 4; ++m)
#pragma unroll
            for (int n = 0; n < 4; ++n)
                acc[m][n] = __builtin_amdgcn_mfma_f32_16x16x32_bf16(
                    af[m], bfr[n], acc[m][n], 0, 0, 0);
        __syncthreads();
    }

    // epilogue: C/D layout col = lane&15, row = (lane>>4)*4 + v
    const int orow = (lane >> 4) * 4;
    float bv[4];
#pragma unroll
    for (int n = 0; n < 4; ++n) bv[n] = bias[bcol + wc * 64 + n * 16 + lr];
#pragma unroll
    for (int m = 0; m < 4; ++m) {
#pragma unroll
        for (int v = 0; v < 4; ++v) {
            const long grow = brow + wr * 64 + m * 16 + orow + v;
            float* cp = C + grow * NDIM + bcol + wc * 64 + lr;
#pragma unroll
            for (int n = 0; n < 4; ++n)
                cp[n * 16] = acc[m][n][v] + bv[n];
        }
    }
}

extern "C" void kernel_launch(void* const* d_in, const int* in_sizes, int n_in,
                              void* d_out, int out_size, void* d_ws, size_t ws_size,
                              hipStream_t stream) {
    const float* x     = (const float*)d_in[0];
    const float* g0    = (const float*)d_in[1];
    const float* g1    = (const float*)d_in[2];
    const float* alpha = (const float*)d_in[3];
    const float* pds   = (const float*)d_in[4];
    const float* bias  = (const float*)d_in[5];
    const int*   iperm = (const int*)d_in[6];
    const int*   oinv  = (const int*)d_in[7];
    float* out = (float*)d_out;

    ushort* W3 = (ushort*)d_ws;                                   // 4096*4096 bf16 = 32MB
    ushort* Xb = (ushort*)d_ws + (size_t)NDIM * KDIM;             // 2048*4096 bf16 = 16MB

    hipLaunchKernelGGL(k_cast, dim3((M_TOK * KDIM) / (256 * 8)), dim3(256), 0, stream, x, Xb);
    hipLaunchKernelGGL(k_w3,   dim3(NDIM), dim3(256), 0, stream, g0, g1, alpha, pds, iperm, oinv, W3);
    hipLaunchKernelGGL(k_gemm, dim3((M_TOK / 128) * (NDIM / 128)), dim3(256), 0, stream, Xb, W3, bias, out);
}

// Round 2
// 120.620 us; speedup vs baseline: 1.0389x; 1.0389x over previous
//
#include <hip/hip_runtime.h>
#include <hip/hip_bf16.h>

#define M_TOK 2048
#define KDIM  4096
#define NDIM  4096
#define BK    64
#define NT    (KDIM / BK)    // 64 K-tiles
#define TILE  (128 * BK)     // ushort elems per LDS tile: 8192 (16 KB)

typedef __bf16 bf16x8 __attribute__((ext_vector_type(8)));
typedef float  f32x4  __attribute__((ext_vector_type(4)));
typedef short  short8 __attribute__((ext_vector_type(8)));

__device__ __forceinline__ ushort f2bf(float f) {
    union { float f; unsigned u; } v; v.f = f;
    unsigned r = (v.u + 0x7fffu + ((v.u >> 16) & 1u)) >> 16;
    return (ushort)r;
}

__device__ __forceinline__ void gload16(const ushort* g, ushort* l) {
    __builtin_amdgcn_global_load_lds(
        (const __attribute__((address_space(1))) void*)g,
        (__attribute__((address_space(3))) void*)l, 16, 0, 0);
}

// ---------------- kernel 1: cast x (fp32) -> bf16 ----------------
__global__ __launch_bounds__(256) void k_cast(const float* __restrict__ x,
                                              ushort* __restrict__ xb) {
    const int i = (blockIdx.x * 256 + threadIdx.x) * 8;
    float4 a = *reinterpret_cast<const float4*>(x + i);
    float4 b = *reinterpret_cast<const float4*>(x + i + 4);
    short8 o;
    o[0] = (short)f2bf(a.x); o[1] = (short)f2bf(a.y);
    o[2] = (short)f2bf(a.z); o[3] = (short)f2bf(a.w);
    o[4] = (short)f2bf(b.x); o[5] = (short)f2bf(b.y);
    o[6] = (short)f2bf(b.z); o[7] = (short)f2bf(b.w);
    *reinterpret_cast<short8*>(xb + i) = o;
}

// ---------------- kernel 2: build fused weight W3 (bf16, N x K) ----------------
__global__ __launch_bounds__(256) void k_w3(const float* __restrict__ g0,
                                            const float* __restrict__ g1,
                                            const float* __restrict__ alpha,
                                            const float* __restrict__ pds,
                                            const int* __restrict__ iperm,
                                            const int* __restrict__ oinv,
                                            ushort* __restrict__ W3) {
    __shared__ float  G0s[1024];   // [j0][r]
    __shared__ float  G1s[1024];   // [r][j1]
    __shared__ ushort rowb[4096];
    const int o  = blockIdx.x;
    const int op = oinv[o];
    const int i0 = op >> 6, i1 = op & 63;
    const float sc = alpha[0] * pds[op];

    for (int idx = threadIdx.x; idx < 1024; idx += 256) {
        G0s[idx] = g0[i0 * 1024 + idx];
        G1s[idx] = g1[(idx >> 6) * 4096 + i1 * 64 + (idx & 63)];
    }
    __syncthreads();
    for (int jp = threadIdx.x; jp < 4096; jp += 256) {
        const int j0 = jp >> 6, j1 = jp & 63;
        float v = 0.f;
#pragma unroll
        for (int r = 0; r < 16; ++r)
            v = fmaf(G0s[j0 * 16 + r], G1s[r * 64 + j1], v);
        rowb[iperm[jp]] = f2bf(v * sc);
    }
    __syncthreads();
    for (int t = threadIdx.x; t < 512; t += 256)
        *reinterpret_cast<short8*>(W3 + (size_t)o * 4096 + t * 8) =
            *reinterpret_cast<const short8*>(rowb + t * 8);
}

// ---------------- kernel 3: C = A @ B^T + bias  (bf16 MFMA, fp32 out) ----------------
// 128x128 tile, BK=64, double-buffered swizzled LDS, 2-phase pipeline.
// LDS layout: [row][colbyte ^ ((row&7)<<4)] within each 128B row.
__global__ __launch_bounds__(256, 2)
void k_gemm(const ushort* __restrict__ A, const ushort* __restrict__ B,
            const float* __restrict__ bias, float* __restrict__ C) {
    __shared__ ushort As[2 * TILE];
    __shared__ ushort Bs[2 * TILE];
    const int tid  = threadIdx.x;
    const int lane = tid & 63;
    const int wave = tid >> 6;

    // XCD-aware bijective swizzle (nwg = 512, divisible by 8)
    const int nbx = NDIM / 128;               // 32
    const int cpx = (M_TOK / 128) * nbx / 8;  // 64
    const int bid = blockIdx.x;
    const int swz = (bid & 7) * cpx + (bid >> 3);
    const int by = swz / nbx, bx = swz % nbx;
    const long brow = (long)by * 128, bcol = (long)bx * 128;

    const int wr = wave >> 1, wc = wave & 1;  // 2x2 waves of 64x64

    f32x4 acc[4][4] = {};

    // ---- staging geometry (per chunk c=0..3): row = c*32 + wave*8 + lane/8
    // global col (elements) pre-swizzled: ((lane&7) ^ (lane>>3)) * 8
    const int srow = wave * 8 + (lane >> 3);
    const int scol = ((lane & 7) ^ (lane >> 3)) << 3;
    const ushort* gA = A + (brow + srow) * KDIM + scol;
    const ushort* gB = B + (bcol + srow) * KDIM + scol;
    const int ldsBase = wave * 512;  // ushort elems; + c*2048 + buf*TILE (lane*16B by HW)

    // ---- fragment-read geometry
    const int lr = lane & 15;
    const int rA = wr * 64 + lr;   // + m*16
    const int rB = wc * 64 + lr;   // + n*16
    // swizzled column (ushort elems) for kk = 0,1
    int colswz[2];
#pragma unroll
    for (int kk = 0; kk < 2; ++kk)
        colswz[kk] = (((kk << 6) | ((lane >> 4) << 4)) ^ ((lane & 7) << 4)) >> 1;

    auto stage = [&](int buf, int kt) {
        const ushort* ga = gA + kt;
        const ushort* gb = gB + kt;
        ushort* la = As + buf * TILE + ldsBase;
        ushort* lb = Bs + buf * TILE + ldsBase;
#pragma unroll
        for (int c = 0; c < 4; ++c) {
            gload16(ga + (size_t)c * 32 * KDIM, la + c * 2048);
            gload16(gb + (size_t)c * 32 * KDIM, lb + c * 2048);
        }
    };

    auto compute = [&](int buf) {
        const ushort* a0 = As + buf * TILE + rA * 64;
        const ushort* b0 = Bs + buf * TILE + rB * 64;
        bf16x8 af[2][4], bfv[2][4];
#pragma unroll
        for (int kk = 0; kk < 2; ++kk) {
#pragma unroll
            for (int m = 0; m < 4; ++m)
                af[kk][m] = *reinterpret_cast<const bf16x8*>(a0 + m * 1024 + colswz[kk]);
#pragma unroll
            for (int n = 0; n < 4; ++n)
                bfv[kk][n] = *reinterpret_cast<const bf16x8*>(b0 + n * 1024 + colswz[kk]);
        }
#pragma unroll
        for (int kk = 0; kk < 2; ++kk)
#pragma unroll
            for (int m = 0; m < 4; ++m)
#pragma unroll
                for (int n = 0; n < 4; ++n)
                    acc[m][n] = __builtin_amdgcn_mfma_f32_16x16x32_bf16(
                        af[kk][m], bfv[kk][n], acc[m][n], 0, 0, 0);
    };

    // prologue: stage tile 0
    stage(0, 0);
    __syncthreads();

    int cur = 0;
    for (int t = 0; t < NT - 1; ++t) {
        stage(cur ^ 1, (t + 1) * BK);  // issue next-tile loads FIRST
        compute(cur);                   // ds_read + MFMA current
        __syncthreads();                // compiler emits vmcnt(0) lgkmcnt(0) here
        cur ^= 1;
    }
    compute(cur);                       // tail, no prefetch

    // epilogue: C/D layout col = lane&15, row = (lane>>4)*4 + v
    const int orow = (lane >> 4) * 4;
    float bv[4];
#pragma unroll
    for (int n = 0; n < 4; ++n) bv[n] = bias[bcol + wc * 64 + n * 16 + lr];
#pragma unroll
    for (int m = 0; m < 4; ++m) {
#pragma unroll
        for (int v = 0; v < 4; ++v) {
            const long grow = brow + wr * 64 + m * 16 + orow + v;
            float* cp = C + grow * NDIM + bcol + wc * 64 + lr;
#pragma unroll
            for (int n = 0; n < 4; ++n)
                cp[n * 16] = acc[m][n][v] + bv[n];
        }
    }
}

extern "C" void kernel_launch(void* const* d_in, const int* in_sizes, int n_in,
                              void* d_out, int out_size, void* d_ws, size_t ws_size,
                              hipStream_t stream) {
    const float* x     = (const float*)d_in[0];
    const float* g0    = (const float*)d_in[1];
    const float* g1    = (const float*)d_in[2];
    const float* alpha = (const float*)d_in[3];
    const float* pds   = (const float*)d_in[4];
    const float* bias  = (const float*)d_in[5];
    const int*   iperm = (const int*)d_in[6];
    const int*   oinv  = (const int*)d_in[7];
    float* out = (float*)d_out;

    ushort* W3 = (ushort*)d_ws;                         // 4096*4096 bf16 = 32MB
    ushort* Xb = (ushort*)d_ws + (size_t)NDIM * KDIM;   // 2048*4096 bf16 = 16MB

    hipLaunchKernelGGL(k_cast, dim3((M_TOK * KDIM) / (256 * 8)), dim3(256), 0, stream, x, Xb);
    hipLaunchKernelGGL(k_w3,   dim3(NDIM), dim3(256), 0, stream, g0, g1, alpha, pds, iperm, oinv, W3);
    hipLaunchKernelGGL(k_gemm, dim3((M_TOK / 128) * (NDIM / 128)), dim3(256), 0, stream, Xb, W3, bias, out);
}

// Round 3
// 113.212 us; speedup vs baseline: 1.1069x; 1.0654x over previous
//
#include <hip/hip_runtime.h>
#include <hip/hip_bf16.h>

#define M_TOK 2048
#define KDIM  4096
#define NDIM  4096
#define BM    128
#define BN    256
#define BK    64
#define NT    (KDIM / BK)          // 64 K-tiles
#define ABUF  (BM * BK)            // 8192 ushorts (16 KB)
#define BBUF  (BN * BK)            // 16384 ushorts (32 KB)
#define BUFSZ (ABUF + BBUF)        // 24576 ushorts (48 KB)

typedef __bf16 bf16x8 __attribute__((ext_vector_type(8)));
typedef float  f32x16 __attribute__((ext_vector_type(16)));
typedef short  short8 __attribute__((ext_vector_type(8)));

__device__ __forceinline__ ushort f2bf(float f) {
    union { float f; unsigned u; } v; v.f = f;
    unsigned r = (v.u + 0x7fffu + ((v.u >> 16) & 1u)) >> 16;
    return (ushort)r;
}

__device__ __forceinline__ void gload16(const ushort* g, ushort* l) {
    __builtin_amdgcn_global_load_lds(
        (const __attribute__((address_space(1))) void*)g,
        (__attribute__((address_space(3))) void*)l, 16, 0, 0);
}

// ---------------- kernel 1: cast x (fp32) -> bf16 ----------------
__global__ __launch_bounds__(256) void k_cast(const float* __restrict__ x,
                                              ushort* __restrict__ xb) {
    const int i = (blockIdx.x * 256 + threadIdx.x) * 8;
    float4 a = *reinterpret_cast<const float4*>(x + i);
    float4 b = *reinterpret_cast<const float4*>(x + i + 4);
    short8 o;
    o[0] = (short)f2bf(a.x); o[1] = (short)f2bf(a.y);
    o[2] = (short)f2bf(a.z); o[3] = (short)f2bf(a.w);
    o[4] = (short)f2bf(b.x); o[5] = (short)f2bf(b.y);
    o[6] = (short)f2bf(b.z); o[7] = (short)f2bf(b.w);
    *reinterpret_cast<short8*>(xb + i) = o;
}

// ---------------- kernel 2: build fused weight W3 (bf16, N x K) ----------------
__global__ __launch_bounds__(256) void k_w3(const float* __restrict__ g0,
                                            const float* __restrict__ g1,
                                            const float* __restrict__ alpha,
                                            const float* __restrict__ pds,
                                            const int* __restrict__ iperm,
                                            const int* __restrict__ oinv,
                                            ushort* __restrict__ W3) {
    __shared__ float  G0s[1024];   // [j0][r]
    __shared__ float  G1s[1024];   // [r][j1]
    __shared__ ushort rowb[4096];
    const int o  = blockIdx.x;
    const int op = oinv[o];
    const int i0 = op >> 6, i1 = op & 63;
    const float sc = alpha[0] * pds[op];

    for (int idx = threadIdx.x; idx < 1024; idx += 256) {
        G0s[idx] = g0[i0 * 1024 + idx];
        G1s[idx] = g1[(idx >> 6) * 4096 + i1 * 64 + (idx & 63)];
    }
    __syncthreads();
    for (int jp = threadIdx.x; jp < 4096; jp += 256) {
        const int j0 = jp >> 6, j1 = jp & 63;
        float v = 0.f;
#pragma unroll
        for (int r = 0; r < 16; ++r)
            v = fmaf(G0s[j0 * 16 + r], G1s[r * 64 + j1], v);
        rowb[iperm[jp]] = f2bf(v * sc);
    }
    __syncthreads();
    for (int t = threadIdx.x; t < 512; t += 256)
        *reinterpret_cast<short8*>(W3 + (size_t)o * 4096 + t * 8) =
            *reinterpret_cast<const short8*>(rowb + t * 8);
}

// ---------------- kernel 3: C = A @ B^T + bias ----------------
// BM=128 x BN=256, BK=64, 512 threads (8 waves 2Mx4N, wave tile 64x64),
// mfma_f32_32x32x16_bf16, triple-buffered swizzled LDS, counted vmcnt(6).
__global__ __launch_bounds__(512, 2)
void k_gemm(const ushort* __restrict__ A, const ushort* __restrict__ B,
            const float* __restrict__ bias, float* __restrict__ C) {
    __shared__ __align__(16) ushort lds[3 * BUFSZ];   // 144 KB
    const int tid  = threadIdx.x;
    const int lane = tid & 63;
    const int w    = tid >> 6;   // 0..7
    const int wr   = w >> 2;     // 0..1 (M)
    const int wc   = w & 3;      // 0..3 (N)

    // XCD-aware bijective swizzle (nwg = 256)
    const int bid = blockIdx.x;
    const int swz = (bid & 7) * 32 + (bid >> 3);
    const long brow = (long)(swz >> 4) * BM;
    const long bcol = (long)(swz & 15) * BN;

    // ---- staging geometry: 6 x gload16 per thread per K-tile.
    // chunk = 8 rows x 64 cols; lane -> row sr=lane>>3, dest slot lane&7;
    // source col pre-swizzled so LDS[row][slot] = global slot (slot ^ (row&7)).
    const int sr = lane >> 3;
    const int sc = ((lane & 7) ^ sr) << 3;
    const ushort* sA0 = A + (brow + w * 8 + sr) * KDIM + sc;
    const ushort* sA1 = sA0 + (size_t)64 * KDIM;
    const ushort* sB0 = B + (bcol + w * 8 + sr) * KDIM + sc;
    const ushort* sB1 = sB0 + (size_t)64 * KDIM;
    const ushort* sB2 = sB0 + (size_t)128 * KDIM;
    const ushort* sB3 = sB0 + (size_t)192 * KDIM;
    const int dA0 = w * 512,        dA1 = 4096 + w * 512;
    const int dB0 = ABUF + w * 512, dB1 = ABUF + 4096 + w * 512;
    const int dB2 = ABUF + 8192 + w * 512, dB3 = ABUF + 12288 + w * 512;

    // ---- fragment-read geometry (32x32x16: row = lane&31, k = (lane>>5)*8 + j)
    const int lane31 = lane & 31;
    const int hb = lane >> 5;
    const ushort* pA = lds + (wr * 64 + lane31) * 64;          // + m*2048 + bufo + cs
    const ushort* pB = lds + ABUF + (wc * 64 + lane31) * 64;   // + n*2048 + bufo + cs
    int cs[4];
#pragma unroll
    for (int ks = 0; ks < 4; ++ks)
        cs[ks] = ((((ks << 1) | hb)) ^ (lane & 7)) << 3;

    f32x16 acc[2][2] = {};

    auto stage = [&](int sbo, int kt) {
        gload16(sA0 + kt, (ushort*)lds + sbo + dA0);
        gload16(sA1 + kt, (ushort*)lds + sbo + dA1);
        gload16(sB0 + kt, (ushort*)lds + sbo + dB0);
        gload16(sB1 + kt, (ushort*)lds + sbo + dB1);
        gload16(sB2 + kt, (ushort*)lds + sbo + dB2);
        gload16(sB3 + kt, (ushort*)lds + sbo + dB3);
    };

    auto compute = [&](int bufo) {
#pragma unroll
        for (int ks = 0; ks < 4; ++ks) {
            bf16x8 a0 = *reinterpret_cast<const bf16x8*>(pA + bufo + cs[ks]);
            bf16x8 a1 = *reinterpret_cast<const bf16x8*>(pA + bufo + 2048 + cs[ks]);
            bf16x8 b0 = *reinterpret_cast<const bf16x8*>(pB + bufo + cs[ks]);
            bf16x8 b1 = *reinterpret_cast<const bf16x8*>(pB + bufo + 2048 + cs[ks]);
            __builtin_amdgcn_s_setprio(1);
            acc[0][0] = __builtin_amdgcn_mfma_f32_32x32x16_bf16(a0, b0, acc[0][0], 0, 0, 0);
            acc[0][1] = __builtin_amdgcn_mfma_f32_32x32x16_bf16(a0, b1, acc[0][1], 0, 0, 0);
            acc[1][0] = __builtin_amdgcn_mfma_f32_32x32x16_bf16(a1, b0, acc[1][0], 0, 0, 0);
            acc[1][1] = __builtin_amdgcn_mfma_f32_32x32x16_bf16(a1, b1, acc[1][1], 0, 0, 0);
            __builtin_amdgcn_s_setprio(0);
        }
    };

    // prologue: stage tiles 0 and 1 (12 loads in flight), wait for tile 0
    stage(0, 0);
    stage(BUFSZ, BK);
    asm volatile("s_waitcnt vmcnt(6)" ::: "memory");
    __builtin_amdgcn_s_barrier();
    asm volatile("" ::: "memory");

    int bufo = 0, sbo = 2 * BUFSZ;
    for (int g = 0; g < NT - 2; ++g) {
        stage(sbo, (g + 2) * BK);   // tile g+2 -> buffer freed at end of group g-1
        compute(bufo);              // tile g
        asm volatile("s_waitcnt vmcnt(6)" ::: "memory");  // tile g+1 landed
        __builtin_amdgcn_s_barrier();
        asm volatile("" ::: "memory");
        bufo = (bufo == 2 * BUFSZ) ? 0 : bufo + BUFSZ;
        sbo  = (sbo  == 2 * BUFSZ) ? 0 : sbo  + BUFSZ;
    }
    compute(bufo);                                        // tile NT-2
    asm volatile("s_waitcnt vmcnt(0)" ::: "memory");      // tile NT-1 landed
    __builtin_amdgcn_s_barrier();
    asm volatile("" ::: "memory");
    bufo = (bufo == 2 * BUFSZ) ? 0 : bufo + BUFSZ;
    compute(bufo);                                        // tile NT-1

    // ---- epilogue: C/D layout col = lane&31, row = (reg&3) + 8*(reg>>2) + 4*hb
    const int  ccol = (int)bcol + wc * 64 + lane31;
    const long row0 = brow + wr * 64 + 4 * hb;
    const float bv0 = bias[ccol];
    const float bv1 = bias[ccol + 32];
#pragma unroll
    for (int m = 0; m < 2; ++m) {
#pragma unroll
        for (int r = 0; r < 16; ++r) {
            const long row = row0 + m * 32 + (r & 3) + 8 * (r >> 2);
            C[row * NDIM + ccol]      = acc[m][0][r] + bv0;
            C[row * NDIM + ccol + 32] = acc[m][1][r] + bv1;
        }
    }
}

extern "C" void kernel_launch(void* const* d_in, const int* in_sizes, int n_in,
                              void* d_out, int out_size, void* d_ws, size_t ws_size,
                              hipStream_t stream) {
    const float* x     = (const float*)d_in[0];
    const float* g0    = (const float*)d_in[1];
    const float* g1    = (const float*)d_in[2];
    const float* alpha = (const float*)d_in[3];
    const float* pds   = (const float*)d_in[4];
    const float* bias  = (const float*)d_in[5];
    const int*   iperm = (const int*)d_in[6];
    const int*   oinv  = (const int*)d_in[7];
    float* out = (float*)d_out;

    ushort* W3 = (ushort*)d_ws;                         // 4096*4096 bf16 = 32MB
    ushort* Xb = (ushort*)d_ws + (size_t)NDIM * KDIM;   // 2048*4096 bf16 = 16MB

    hipLaunchKernelGGL(k_cast, dim3((M_TOK * KDIM) / (256 * 8)), dim3(256), 0, stream, x, Xb);
    hipLaunchKernelGGL(k_w3,   dim3(NDIM), dim3(256), 0, stream, g0, g1, alpha, pds, iperm, oinv, W3);
    hipLaunchKernelGGL(k_gemm, dim3((M_TOK / BM) * (NDIM / BN)), dim3(512), 0, stream, Xb, W3, bias, out);
}

// Round 4
// 112.420 us; speedup vs baseline: 1.1147x; 1.0070x over previous
//
#include <hip/hip_runtime.h>
#include <hip/hip_bf16.h>

#define M_TOK 2048
#define KDIM  4096
#define NDIM  4096
#define BM    128
#define BN    256
#define BK    32
#define NT    (KDIM / BK)          // 128 K-tiles
#define ABUF  (BM * BK)            // 4096 ushorts (8 KB)
#define BBUF  (BN * BK)            // 8192 ushorts (16 KB)
#define BUFSZ (ABUF + BBUF)        // 12288 ushorts (24 KB)
#define NBUF  6                    // 144 KB LDS, prefetch depth 5

typedef __bf16 bf16x8 __attribute__((ext_vector_type(8)));
typedef float  f32x16 __attribute__((ext_vector_type(16)));
typedef short  short8 __attribute__((ext_vector_type(8)));

__device__ __forceinline__ ushort f2bf(float f) {
    union { float f; unsigned u; } v; v.f = f;
    unsigned r = (v.u + 0x7fffu + ((v.u >> 16) & 1u)) >> 16;
    return (ushort)r;
}

__device__ __forceinline__ void gload16(const ushort* g, ushort* l) {
    __builtin_amdgcn_global_load_lds(
        (const __attribute__((address_space(1))) void*)g,
        (__attribute__((address_space(3))) void*)l, 16, 0, 0);
}

// ---------------- kernel 1: cast x (fp32) -> bf16 ----------------
__global__ __launch_bounds__(256) void k_cast(const float* __restrict__ x,
                                              ushort* __restrict__ xb) {
    const int i = (blockIdx.x * 256 + threadIdx.x) * 8;
    float4 a = *reinterpret_cast<const float4*>(x + i);
    float4 b = *reinterpret_cast<const float4*>(x + i + 4);
    short8 o;
    o[0] = (short)f2bf(a.x); o[1] = (short)f2bf(a.y);
    o[2] = (short)f2bf(a.z); o[3] = (short)f2bf(a.w);
    o[4] = (short)f2bf(b.x); o[5] = (short)f2bf(b.y);
    o[6] = (short)f2bf(b.z); o[7] = (short)f2bf(b.w);
    *reinterpret_cast<short8*>(xb + i) = o;
}

// ---------------- kernel 2: build fused weight W3 (bf16, N x K) ----------------
__global__ __launch_bounds__(256) void k_w3(const float* __restrict__ g0,
                                            const float* __restrict__ g1,
                                            const float* __restrict__ alpha,
                                            const float* __restrict__ pds,
                                            const int* __restrict__ iperm,
                                            const int* __restrict__ oinv,
                                            ushort* __restrict__ W3) {
    __shared__ float  G0s[1024];   // [j0][r]
    __shared__ float  G1s[1024];   // [r][j1]
    __shared__ ushort rowb[4096];
    const int o  = blockIdx.x;
    const int op = oinv[o];
    const int i0 = op >> 6, i1 = op & 63;
    const float sc = alpha[0] * pds[op];

    for (int idx = threadIdx.x; idx < 1024; idx += 256) {
        G0s[idx] = g0[i0 * 1024 + idx];
        G1s[idx] = g1[(idx >> 6) * 4096 + i1 * 64 + (idx & 63)];
    }
    __syncthreads();
    for (int jp = threadIdx.x; jp < 4096; jp += 256) {
        const int j0 = jp >> 6, j1 = jp & 63;
        float v = 0.f;
#pragma unroll
        for (int r = 0; r < 16; ++r)
            v = fmaf(G0s[j0 * 16 + r], G1s[r * 64 + j1], v);
        rowb[iperm[jp]] = f2bf(v * sc);
    }
    __syncthreads();
    for (int t = threadIdx.x; t < 512; t += 256)
        *reinterpret_cast<short8*>(W3 + (size_t)o * 4096 + t * 8) =
            *reinterpret_cast<const short8*>(rowb + t * 8);
}

// ---------------- kernel 3: C = A @ B^T + bias ----------------
// BM=128 x BN=256, BK=32, 512 threads (8 waves 2Mx4N, wave tile 64x64),
// mfma_f32_32x32x16_bf16, 6-buffer LDS ring (depth-5 prefetch), vmcnt(12).
// LDS rows = 64B = 4 x 16B slots; slot swizzle: LDS slot = g ^ ((row>>1)&3).
__global__ __launch_bounds__(512, 2)
void k_gemm(const ushort* __restrict__ A, const ushort* __restrict__ B,
            const float* __restrict__ bias, float* __restrict__ C) {
    __shared__ __align__(16) ushort lds[NBUF * BUFSZ];   // 144 KB
    const int tid  = threadIdx.x;
    const int lane = tid & 63;
    const int w    = tid >> 6;   // 0..7
    const int wr   = w >> 2;     // 0..1 (M)
    const int wc   = w & 3;      // 0..3 (N)

    // XCD mapping: each XCD owns a 4(by) x 8(bx) rectangle of the 16x16 grid
    const int bid = blockIdx.x;
    const int xcd = bid & 7, li = bid >> 3;
    const int by = (xcd >> 1) * 4 + (li >> 3);
    const int bx = (xcd & 1) * 8 + (li & 7);
    const long brow = (long)by * BM, bcol = (long)bx * BN;

    // ---- staging: 3 gload16/thread/tile. chunk = (row, slot): A chunk tid,
    // B chunks tid and 512+tid. row = chunk>>2, LDS slot = chunk&3,
    // global slot g = slot ^ ((row>>1)&3)  (identical for all 3 chunks).
    const int ra = tid >> 2;
    const int g8 = (((tid & 3) ^ ((ra >> 1) & 3)) << 3);
    const ushort* sA  = A + (size_t)(brow + ra) * KDIM + g8;
    const ushort* sB0 = B + (size_t)(bcol + ra) * KDIM + g8;
    const ushort* sB1 = sB0 + (size_t)128 * KDIM;
    const int dA  = tid * 8;
    const int dB0 = ABUF + tid * 8;
    const int dB1 = ABUF + 4096 + tid * 8;

    // ---- fragment reads (32x32x16): row = lane&31 (+m*32), k-chunk g = 2ks+hb
    const int lane31 = lane & 31;
    const int hb = lane >> 5;
    const int rxor = (lane31 >> 1) & 3;
    int cs[2];
#pragma unroll
    for (int ks = 0; ks < 2; ++ks)
        cs[ks] = (((ks << 1) | hb) ^ rxor) << 3;
    const ushort* pA = lds + (wr * 64 + lane31) * 32;          // + m*1024 + bufo + cs
    const ushort* pB = lds + ABUF + (wc * 64 + lane31) * 32;   // + n*1024 + bufo + cs

    f32x16 acc[2][2] = {};

    auto stage = [&](int sbo, int kt) {
        gload16(sA  + kt, (ushort*)lds + sbo + dA);
        gload16(sB0 + kt, (ushort*)lds + sbo + dB0);
        gload16(sB1 + kt, (ushort*)lds + sbo + dB1);
    };

    auto compute = [&](int bufo) {
#pragma unroll
        for (int ks = 0; ks < 2; ++ks) {
            bf16x8 a0 = *reinterpret_cast<const bf16x8*>(pA + bufo + cs[ks]);
            bf16x8 a1 = *reinterpret_cast<const bf16x8*>(pA + bufo + 1024 + cs[ks]);
            bf16x8 b0 = *reinterpret_cast<const bf16x8*>(pB + bufo + cs[ks]);
            bf16x8 b1 = *reinterpret_cast<const bf16x8*>(pB + bufo + 1024 + cs[ks]);
            __builtin_amdgcn_s_setprio(1);
            acc[0][0] = __builtin_amdgcn_mfma_f32_32x32x16_bf16(a0, b0, acc[0][0], 0, 0, 0);
            acc[0][1] = __builtin_amdgcn_mfma_f32_32x32x16_bf16(a0, b1, acc[0][1], 0, 0, 0);
            acc[1][0] = __builtin_amdgcn_mfma_f32_32x32x16_bf16(a1, b0, acc[1][0], 0, 0, 0);
            acc[1][1] = __builtin_amdgcn_mfma_f32_32x32x16_bf16(a1, b1, acc[1][1], 0, 0, 0);
            __builtin_amdgcn_s_setprio(0);
        }
    };

    // prologue: stage tiles 0..4 (15 loads in flight)
#pragma unroll
    for (int p = 0; p < 5; ++p) stage(p * BUFSZ, p * BK);

    int bufo = 0, sbo = 5 * BUFSZ;
    for (int g = 0; g <= NT - 6; ++g) {
        asm volatile("s_waitcnt vmcnt(12)" ::: "memory");   // tile g landed
        __builtin_amdgcn_s_barrier();
        asm volatile("" ::: "memory");
        stage(sbo, (g + 5) * BK);   // buf holds tile g-1: all waves done with it
        compute(bufo);              // tile g
        bufo = (bufo == (NBUF - 1) * BUFSZ) ? 0 : bufo + BUFSZ;
        sbo  = (sbo  == (NBUF - 1) * BUFSZ) ? 0 : sbo  + BUFSZ;
    }
    // tail: tiles NT-5..NT-1, outstanding 15 -> 12,9,6,3,0
#define TAILSTEP(NLIT)                                          \
    asm volatile("s_waitcnt vmcnt(" #NLIT ")" ::: "memory");    \
    __builtin_amdgcn_s_barrier();                               \
    asm volatile("" ::: "memory");                              \
    compute(bufo);                                              \
    bufo = (bufo == (NBUF - 1) * BUFSZ) ? 0 : bufo + BUFSZ;
    TAILSTEP(12) TAILSTEP(9) TAILSTEP(6) TAILSTEP(3) TAILSTEP(0)
#undef TAILSTEP

    // ---- epilogue: C/D layout col = lane&31, row = (reg&3) + 8*(reg>>2) + 4*hb
    const int  ccol = (int)bcol + wc * 64 + lane31;
    const long row0 = brow + wr * 64 + 4 * hb;
    const float bv0 = bias[ccol];
    const float bv1 = bias[ccol + 32];
#pragma unroll
    for (int m = 0; m < 2; ++m) {
#pragma unroll
        for (int r = 0; r < 16; ++r) {
            const long row = row0 + m * 32 + (r & 3) + 8 * (r >> 2);
            C[row * NDIM + ccol]      = acc[m][0][r] + bv0;
            C[row * NDIM + ccol + 32] = acc[m][1][r] + bv1;
        }
    }
}

extern "C" void kernel_launch(void* const* d_in, const int* in_sizes, int n_in,
                              void* d_out, int out_size, void* d_ws, size_t ws_size,
                              hipStream_t stream) {
    const float* x     = (const float*)d_in[0];
    const float* g0    = (const float*)d_in[1];
    const float* g1    = (const float*)d_in[2];
    const float* alpha = (const float*)d_in[3];
    const float* pds   = (const float*)d_in[4];
    const float* bias  = (const float*)d_in[5];
    const int*   iperm = (const int*)d_in[6];
    const int*   oinv  = (const int*)d_in[7];
    float* out = (float*)d_out;

    ushort* W3 = (ushort*)d_ws;                         // 4096*4096 bf16 = 32MB
    ushort* Xb = (ushort*)d_ws + (size_t)NDIM * KDIM;   // 2048*4096 bf16 = 16MB

    hipLaunchKernelGGL(k_cast, dim3((M_TOK * KDIM) / (256 * 8)), dim3(256), 0, stream, x, Xb);
    hipLaunchKernelGGL(k_w3,   dim3(NDIM), dim3(256), 0, stream, g0, g1, alpha, pds, iperm, oinv, W3);
    hipLaunchKernelGGL(k_gemm, dim3((M_TOK / BM) * (NDIM / BN)), dim3(512), 0, stream, Xb, W3, bias, out);
}

// Round 5
// 104.491 us; speedup vs baseline: 1.1993x; 1.0759x over previous
//
#include <hip/hip_runtime.h>
#include <hip/hip_bf16.h>

#define M_TOK 2048
#define KDIM  4096
#define NDIM  4096
#define BM    128
#define BN    128
#define BK    64
#define NT    (KDIM / BK)          // 64 K-tiles
#define ATILE (BM * BK)            // 8192 ushorts (16 KB)
#define BUFSZ (2 * ATILE)          // A+B per buffer: 16384 ushorts (32 KB)

typedef __bf16 bf16x8 __attribute__((ext_vector_type(8)));
typedef float  f32x4  __attribute__((ext_vector_type(4)));
typedef short  short8 __attribute__((ext_vector_type(8)));

__device__ __forceinline__ ushort f2bf(float f) {
    union { float f; unsigned u; } v; v.f = f;
    unsigned r = (v.u + 0x7fffu + ((v.u >> 16) & 1u)) >> 16;
    return (ushort)r;
}

__device__ __forceinline__ void gload16(const ushort* g, ushort* l) {
    __builtin_amdgcn_global_load_lds(
        (const __attribute__((address_space(1))) void*)g,
        (__attribute__((address_space(3))) void*)l, 16, 0, 0);
}

// ---------------- kernel 1: cast x (fp32) -> bf16 ----------------
__global__ __launch_bounds__(256) void k_cast(const float* __restrict__ x,
                                              ushort* __restrict__ xb) {
    const int i = (blockIdx.x * 256 + threadIdx.x) * 8;
    float4 a = *reinterpret_cast<const float4*>(x + i);
    float4 b = *reinterpret_cast<const float4*>(x + i + 4);
    short8 o;
    o[0] = (short)f2bf(a.x); o[1] = (short)f2bf(a.y);
    o[2] = (short)f2bf(a.z); o[3] = (short)f2bf(a.w);
    o[4] = (short)f2bf(b.x); o[5] = (short)f2bf(b.y);
    o[6] = (short)f2bf(b.z); o[7] = (short)f2bf(b.w);
    *reinterpret_cast<short8*>(xb + i) = o;
}

// ---------------- kernel 2: build fused weight W3 (bf16, N x K) ----------------
__global__ __launch_bounds__(256) void k_w3(const float* __restrict__ g0,
                                            const float* __restrict__ g1,
                                            const float* __restrict__ alpha,
                                            const float* __restrict__ pds,
                                            const int* __restrict__ iperm,
                                            const int* __restrict__ oinv,
                                            ushort* __restrict__ W3) {
    __shared__ float  G0s[1024];   // [j0][r]
    __shared__ float  G1s[1024];   // [r][j1]
    __shared__ ushort rowb[4096];
    const int o  = blockIdx.x;
    const int op = oinv[o];
    const int i0 = op >> 6, i1 = op & 63;
    const float sc = alpha[0] * pds[op];

    for (int idx = threadIdx.x; idx < 1024; idx += 256) {
        G0s[idx] = g0[i0 * 1024 + idx];
        G1s[idx] = g1[(idx >> 6) * 4096 + i1 * 64 + (idx & 63)];
    }
    __syncthreads();
    for (int jp = threadIdx.x; jp < 4096; jp += 256) {
        const int j0 = jp >> 6, j1 = jp & 63;
        float v = 0.f;
#pragma unroll
        for (int r = 0; r < 16; ++r)
            v = fmaf(G0s[j0 * 16 + r], G1s[r * 64 + j1], v);
        rowb[iperm[jp]] = f2bf(v * sc);
    }
    __syncthreads();
    for (int t = threadIdx.x; t < 512; t += 256)
        *reinterpret_cast<short8*>(W3 + (size_t)o * 4096 + t * 8) =
            *reinterpret_cast<const short8*>(rowb + t * 8);
}

// ---------------- kernel 3: C = A @ B^T + bias ----------------
// 128x128 tile, 4 waves (2x2 of 64x64), BK=64, 16x16x32 MFMA,
// Round-2-verified zero-conflict LDS swizzle (byte ^= (row&7)<<4, 128B rows),
// NBUF=2 ring with counted vmcnt(8); grid 512 -> 2 blocks/CU (64KB LDS each).
__global__ __launch_bounds__(256, 2)
void k_gemm(const ushort* __restrict__ A, const ushort* __restrict__ B,
            const float* __restrict__ bias, float* __restrict__ C) {
    __shared__ __align__(16) ushort lds[2 * BUFSZ];   // 64 KB
    const int tid  = threadIdx.x;
    const int lane = tid & 63;
    const int wave = tid >> 6;

    // XCD mapping: 512 blocks, each XCD owns 2 full by-rows (A slice L2-resident)
    const int bid = blockIdx.x;
    const int swz = (bid & 7) * 64 + (bid >> 3);
    const int by = swz >> 5, bx = swz & 31;
    const long brow = (long)by * BM, bcol = (long)bx * BN;

    const int wr = wave >> 1, wc = wave & 1;  // 2x2 waves of 64x64

    f32x4 acc[4][4] = {};

    // ---- staging (Round-2 geometry): per chunk c: 32 rows x 64 cols.
    // thread covers row w*8 + (lane>>3), LDS slot lane&7,
    // global slot pre-swizzled: (lane&7) ^ (lane>>3)  [= slot ^ (row&7)]
    const int srow = wave * 8 + (lane >> 3);
    const int scol = ((lane & 7) ^ (lane >> 3)) << 3;
    const ushort* gA = A + (brow + srow) * KDIM + scol;
    const ushort* gB = B + (bcol + srow) * KDIM + scol;
    const int ldsBase = wave * 512;   // + c*2048 (+ lane*16B by HW)

    // ---- fragment-read geometry (Round-2 exact)
    const int lr = lane & 15;
    const int rA = wr * 64 + lr;
    const int rB = wc * 64 + lr;
    int colswz[2];
#pragma unroll
    for (int kk = 0; kk < 2; ++kk)
        colswz[kk] = (((kk << 6) | ((lane >> 4) << 4)) ^ ((lane & 7) << 4)) >> 1;
    const int paOff = rA * 64;
    const int pbOff = ATILE + rB * 64;

    auto stage = [&](int buf, int kt) {
        const ushort* ga = gA + kt;
        const ushort* gb = gB + kt;
        ushort* la = (ushort*)lds + buf + ldsBase;
        ushort* lb = (ushort*)lds + buf + ATILE + ldsBase;
#pragma unroll
        for (int c = 0; c < 4; ++c) {
            gload16(ga + (size_t)c * 32 * KDIM, la + c * 2048);
            gload16(gb + (size_t)c * 32 * KDIM, lb + c * 2048);
        }
    };

    auto compute = [&](int buf) {
        const ushort* a0 = lds + buf + paOff;
        const ushort* b0 = lds + buf + pbOff;
        bf16x8 af[2][4], bfv[2][4];
#pragma unroll
        for (int kk = 0; kk < 2; ++kk) {
#pragma unroll
            for (int m = 0; m < 4; ++m)
                af[kk][m] = *reinterpret_cast<const bf16x8*>(a0 + m * 1024 + colswz[kk]);
#pragma unroll
            for (int n = 0; n < 4; ++n)
                bfv[kk][n] = *reinterpret_cast<const bf16x8*>(b0 + n * 1024 + colswz[kk]);
        }
        __builtin_amdgcn_s_setprio(1);
#pragma unroll
        for (int kk = 0; kk < 2; ++kk)
#pragma unroll
            for (int m = 0; m < 4; ++m)
#pragma unroll
                for (int n = 0; n < 4; ++n)
                    acc[m][n] = __builtin_amdgcn_mfma_f32_16x16x32_bf16(
                        af[kk][m], bfv[kk][n], acc[m][n], 0, 0, 0);
        __builtin_amdgcn_s_setprio(0);
    };

    // prologue: stage tiles 0 and 1 (16 loads), wait tile 0 (8 remain in flight)
    stage(0, 0);
    stage(BUFSZ, BK);
    asm volatile("s_waitcnt vmcnt(8)" ::: "memory");
    __builtin_amdgcn_s_barrier();

    int buf = 0;
    for (int g = 0; g < NT; ++g) {
        compute(buf);                       // tile g (landed, all waves)
        if (g == NT - 1) break;
        __builtin_amdgcn_s_barrier();       // all reads of tile g done
        if (g + 2 < NT) {
            stage(buf, (g + 2) * BK);       // overwrite tile g's buffer
            asm volatile("s_waitcnt vmcnt(8)" ::: "memory");  // tile g+1 landed
        } else {
            asm volatile("s_waitcnt vmcnt(0)" ::: "memory");  // last tile landed
        }
        __builtin_amdgcn_s_barrier();       // landing visible to all waves
        buf ^= BUFSZ;
    }

    // ---- epilogue (Round-2 verified): col = lane&15, row = (lane>>4)*4 + v
    const int orow = (lane >> 4) * 4;
    float bv[4];
#pragma unroll
    for (int n = 0; n < 4; ++n) bv[n] = bias[bcol + wc * 64 + n * 16 + lr];
#pragma unroll
    for (int m = 0; m < 4; ++m) {
#pragma unroll
        for (int v = 0; v < 4; ++v) {
            const long grow = brow + wr * 64 + m * 16 + orow + v;
            float* cp = C + grow * NDIM + bcol + wc * 64 + lr;
#pragma unroll
            for (int n = 0; n < 4; ++n)
                cp[n * 16] = acc[m][n][v] + bv[n];
        }
    }
}

extern "C" void kernel_launch(void* const* d_in, const int* in_sizes, int n_in,
                              void* d_out, int out_size, void* d_ws, size_t ws_size,
                              hipStream_t stream) {
    const float* x     = (const float*)d_in[0];
    const float* g0    = (const float*)d_in[1];
    const float* g1    = (const float*)d_in[2];
    const float* alpha = (const float*)d_in[3];
    const float* pds   = (const float*)d_in[4];
    const float* bias  = (const float*)d_in[5];
    const int*   iperm = (const int*)d_in[6];
    const int*   oinv  = (const int*)d_in[7];
    float* out = (float*)d_out;

    ushort* W3 = (ushort*)d_ws;                         // 4096*4096 bf16 = 32MB
    ushort* Xb = (ushort*)d_ws + (size_t)NDIM * KDIM;   // 2048*4096 bf16 = 16MB

    hipLaunchKernelGGL(k_cast, dim3((M_TOK * KDIM) / (256 * 8)), dim3(256), 0, stream, x, Xb);
    hipLaunchKernelGGL(k_w3,   dim3(NDIM), dim3(256), 0, stream, g0, g1, alpha, pds, iperm, oinv, W3);
    hipLaunchKernelGGL(k_gemm, dim3((M_TOK / BM) * (NDIM / BN)), dim3(256), 0, stream, Xb, W3, bias, out);
}

// Round 6
// 100.926 us; speedup vs baseline: 1.2417x; 1.0353x over previous
//
#include <hip/hip_runtime.h>
#include <hip/hip_bf16.h>

#define M_TOK 2048
#define KDIM  4096
#define NDIM  4096
#define BM    256
#define BN    128
#define BK    64
#define NT    (KDIM / BK)          // 64 K-tiles
#define NI    (NT / 2)             // 32 iters (2 tiles each)
#define AREG  (BM * BK)            // 16384 ushorts (32 KB)
#define BREG  (BN * BK)            // 8192 ushorts (16 KB)
#define BUFSZ (AREG + BREG)        // 24576 ushorts (48 KB)

typedef __bf16 bf16x8 __attribute__((ext_vector_type(8)));
typedef float  f32x4  __attribute__((ext_vector_type(4)));
typedef short  short8 __attribute__((ext_vector_type(8)));

__device__ __forceinline__ ushort f2bf(float f) {
    union { float f; unsigned u; } v; v.f = f;
    unsigned r = (v.u + 0x7fffu + ((v.u >> 16) & 1u)) >> 16;
    return (ushort)r;
}

__device__ __forceinline__ void gload16(const ushort* g, ushort* l) {
    __builtin_amdgcn_global_load_lds(
        (const __attribute__((address_space(1))) void*)g,
        (__attribute__((address_space(3))) void*)l, 16, 0, 0);
}

// ---------------- kernel 1: cast x (fp32) -> bf16 ----------------
__global__ __launch_bounds__(256) void k_cast(const float* __restrict__ x,
                                              ushort* __restrict__ xb) {
    const int i = (blockIdx.x * 256 + threadIdx.x) * 8;
    float4 a = *reinterpret_cast<const float4*>(x + i);
    float4 b = *reinterpret_cast<const float4*>(x + i + 4);
    short8 o;
    o[0] = (short)f2bf(a.x); o[1] = (short)f2bf(a.y);
    o[2] = (short)f2bf(a.z); o[3] = (short)f2bf(a.w);
    o[4] = (short)f2bf(b.x); o[5] = (short)f2bf(b.y);
    o[6] = (short)f2bf(b.z); o[7] = (short)f2bf(b.w);
    *reinterpret_cast<short8*>(xb + i) = o;
}

// ---------------- kernel 2: build fused weight W3 (bf16, N x K) ----------------
__global__ __launch_bounds__(256) void k_w3(const float* __restrict__ g0,
                                            const float* __restrict__ g1,
                                            const float* __restrict__ alpha,
                                            const float* __restrict__ pds,
                                            const int* __restrict__ iperm,
                                            const int* __restrict__ oinv,
                                            ushort* __restrict__ W3) {
    __shared__ float  G0s[1024];   // [j0][r]
    __shared__ float  G1s[1024];   // [r][j1]
    __shared__ ushort rowb[4096];
    const int o  = blockIdx.x;
    const int op = oinv[o];
    const int i0 = op >> 6, i1 = op & 63;
    const float sc = alpha[0] * pds[op];

    for (int idx = threadIdx.x; idx < 1024; idx += 256) {
        G0s[idx] = g0[i0 * 1024 + idx];
        G1s[idx] = g1[(idx >> 6) * 4096 + i1 * 64 + (idx & 63)];
    }
    __syncthreads();
    for (int jp = threadIdx.x; jp < 4096; jp += 256) {
        const int j0 = jp >> 6, j1 = jp & 63;
        float v = 0.f;
#pragma unroll
        for (int r = 0; r < 16; ++r)
            v = fmaf(G0s[j0 * 16 + r], G1s[r * 64 + j1], v);
        rowb[iperm[jp]] = f2bf(v * sc);
    }
    __syncthreads();
    for (int t = threadIdx.x; t < 512; t += 256)
        *reinterpret_cast<short8*>(W3 + (size_t)o * 4096 + t * 8) =
            *reinterpret_cast<const short8*>(rowb + t * 8);
}

// ---------------- kernel 3: C = A @ B^T + bias ----------------
// BM=256 x BN=128, BK=64, 512 thr (8 waves 2Mx4N, wave tile 128x32),
// 16x16x32 MFMA, dbuf LDS (96KB), 2-phase/K-tile schedule with per-phase
// {ds_read | quarter-unit gload | MFMA} interleave, counted vmcnt(2),
// R5-verified zero-conflict swizzle (byte ^= (row&7)<<4, 128B rows).
__global__ __launch_bounds__(512, 2)
void k_gemm(const ushort* __restrict__ A, const ushort* __restrict__ B,
            const float* __restrict__ bias, float* __restrict__ C) {
    __shared__ __align__(16) ushort lds[2 * BUFSZ];   // 96 KB
    const int tid  = threadIdx.x;
    const int lane = tid & 63;
    const int w    = tid >> 6;   // 0..7
    const int wr   = w >> 2;     // 0..1 (M): rows wr*128
    const int wc   = w & 3;      // 0..3 (N): cols wc*32

    // XCD mapping: 8x32 block grid; each XCD owns a 4(by) x 8(bx) rectangle
    const int bid = blockIdx.x;
    const int xcd = bid & 7, li = bid >> 3;
    const int by = (xcd >> 2) * 4 + (li >> 3);   // 0..7
    const int bx = (xcd & 3) * 8 + (li & 7);     // 0..31
    const long brow = (long)by * BM, bcol = (long)bx * BN;

    // ---- staging: quarter-units of 64 rows x 64 cols (8KB, 1 gload/thread).
    // thread t -> row t>>3, LDS 16B-slot t&7; global slot pre-swizzled ^ (row&7)
    const int rhat = tid >> 3;
    const int scol = ((tid & 7) ^ (rhat & 7)) << 3;
    const ushort* gA0 = A + (size_t)(brow + rhat) * KDIM + scol;
    const ushort* gB0 = B + (size_t)(bcol + rhat) * KDIM + scol;
    const int wub = (tid & ~63) * 8;   // per-wave uniform LDS base (ushorts)

    auto stA = [&](int bufo, int q, int kt) {
        gload16(gA0 + (size_t)(q << 6) * KDIM + kt, (ushort*)lds + bufo + q * 4096 + wub);
    };
    auto stB = [&](int bufo, int q, int kt) {
        gload16(gB0 + (size_t)(q << 6) * KDIM + kt, (ushort*)lds + bufo + AREG + q * 4096 + wub);
    };

    // ---- fragment-read geometry (R5-verified swizzle)
    const int lr = lane & 15;
    const int rowA = (wr * 128 + lr) * 64;           // + m*1024
    const int rowB = (wc * 32 + lr) * 64;            // + n*1024 (within B region)
    int colswz[2];
#pragma unroll
    for (int kk = 0; kk < 2; ++kk)
        colswz[kk] = (((kk << 6) | ((lane >> 4) << 4)) ^ ((lane & 7) << 4)) >> 1;

    f32x4 acc[8][2] = {};

#define VM2 asm volatile("s_waitcnt vmcnt(2)" ::: "memory")
#define VM0 asm volatile("s_waitcnt vmcnt(0)" ::: "memory")
#define PHASE(MH, BUFO, STAGE_STMT, TAIL_STMT)                                 \
    do {                                                                       \
        bf16x8 af[4][2], bfr[2][2];                                            \
        _Pragma("unroll") for (int mm = 0; mm < 4; ++mm)                       \
            _Pragma("unroll") for (int kk = 0; kk < 2; ++kk)                   \
                af[mm][kk] = *reinterpret_cast<const bf16x8*>(                 \
                    lds + (BUFO) + rowA + ((MH) * 4 + mm) * 1024 + colswz[kk]);\
        _Pragma("unroll") for (int nn = 0; nn < 2; ++nn)                       \
            _Pragma("unroll") for (int kk = 0; kk < 2; ++kk)                   \
                bfr[nn][kk] = *reinterpret_cast<const bf16x8*>(                \
                    lds + (BUFO) + AREG + rowB + nn * 1024 + colswz[kk]);      \
        STAGE_STMT;                                                            \
        __builtin_amdgcn_s_setprio(1);                                         \
        _Pragma("unroll") for (int mm = 0; mm < 4; ++mm)                       \
            _Pragma("unroll") for (int nn = 0; nn < 2; ++nn)                   \
                _Pragma("unroll") for (int kk = 0; kk < 2; ++kk)               \
                    acc[(MH) * 4 + mm][nn] =                                   \
                        __builtin_amdgcn_mfma_f32_16x16x32_bf16(               \
                            af[mm][kk], bfr[nn][kk], acc[(MH) * 4 + mm][nn],   \
                            0, 0, 0);                                          \
        __builtin_amdgcn_s_setprio(0);                                         \
        TAIL_STMT;                                                             \
        asm volatile("" ::: "memory");                                         \
        __builtin_amdgcn_s_barrier();                                          \
        asm volatile("" ::: "memory");                                         \
    } while (0)

    const int b0 = 0, b1 = BUFSZ;   // even tiles -> buf0, odd -> buf1

    // prologue: tile0 full (6 units) + tile1 A-q0,q2 ; wait tile0 landed
    stA(b0, 0, 0); stA(b0, 1, 0); stA(b0, 2, 0); stA(b0, 3, 0);
    stB(b0, 0, 0); stB(b0, 1, 0);
    stA(b1, 0, BK); stA(b1, 2, BK);
    VM2;
    asm volatile("" ::: "memory");
    __builtin_amdgcn_s_barrier();
    asm volatile("" ::: "memory");

    for (int i = 0; i < NI - 1; ++i) {
        const int k1 = (2 * i + 1) * BK, k2 = (2 * i + 2) * BK, k3 = (2 * i + 3) * BK;
        // Ph1: tile 2i mh0 | stage tile 2i+1 rest -> buf1 (dead: prev iter)
        PHASE(0, b0, { stA(b1, 1, k1); stA(b1, 3, k1); stB(b1, 0, k1); stB(b1, 1, k1); }, );
        // Ph2: tile 2i mh1 | stage tile 2i+2 A-q0,q2 -> buf0 (dead at Ph1 end)
        PHASE(1, b0, { stA(b0, 0, k2); stA(b0, 2, k2); }, VM2);
        // Ph3: tile 2i+1 mh0 | stage tile 2i+2 rest -> buf0 (dead at Ph2 end)
        PHASE(0, b1, { stA(b0, 1, k2); stA(b0, 3, k2); stB(b0, 0, k2); stB(b0, 1, k2); }, );
        // Ph4: tile 2i+1 mh1 | stage tile 2i+3 A-q0,q2 -> buf1 (dead at Ph3 end)
        PHASE(1, b1, { stA(b1, 0, k3); stA(b1, 2, k3); }, VM2);
    }
    // last iter: tiles NT-2 (buf0), NT-1 (buf1); no staging beyond NT-1
    {
        const int k1 = (NT - 1) * BK;
        PHASE(0, b0, { stA(b1, 1, k1); stA(b1, 3, k1); stB(b1, 0, k1); stB(b1, 1, k1); }, );
        PHASE(1, b0, {}, VM0);
        PHASE(0, b1, {}, );
        PHASE(1, b1, {}, );
    }
#undef PHASE
#undef VM2
#undef VM0

    // ---- epilogue: C/D layout col = lane&15, row = (lane>>4)*4 + v
    const int orow = (lane >> 4) * 4;
    float bv[2];
#pragma unroll
    for (int n = 0; n < 2; ++n) bv[n] = bias[bcol + wc * 32 + n * 16 + lr];
#pragma unroll
    for (int m = 0; m < 8; ++m) {
#pragma unroll
        for (int v = 0; v < 4; ++v) {
            const long grow = brow + wr * 128 + m * 16 + orow + v;
            float* cp = C + grow * NDIM + bcol + wc * 32 + lr;
#pragma unroll
            for (int n = 0; n < 2; ++n)
                cp[n * 16] = acc[m][n][v] + bv[n];
        }
    }
}

extern "C" void kernel_launch(void* const* d_in, const int* in_sizes, int n_in,
                              void* d_out, int out_size, void* d_ws, size_t ws_size,
                              hipStream_t stream) {
    const float* x     = (const float*)d_in[0];
    const float* g0    = (const float*)d_in[1];
    const float* g1    = (const float*)d_in[2];
    const float* alpha = (const float*)d_in[3];
    const float* pds   = (const float*)d_in[4];
    const float* bias  = (const float*)d_in[5];
    const int*   iperm = (const int*)d_in[6];
    const int*   oinv  = (const int*)d_in[7];
    float* out = (float*)d_out;

    ushort* W3 = (ushort*)d_ws;                         // 4096*4096 bf16 = 32MB
    ushort* Xb = (ushort*)d_ws + (size_t)NDIM * KDIM;   // 2048*4096 bf16 = 16MB

    hipLaunchKernelGGL(k_cast, dim3((M_TOK * KDIM) / (256 * 8)), dim3(256), 0, stream, x, Xb);
    hipLaunchKernelGGL(k_w3,   dim3(NDIM), dim3(256), 0, stream, g0, g1, alpha, pds, iperm, oinv, W3);
    hipLaunchKernelGGL(k_gemm, dim3((M_TOK / BM) * (NDIM / BN)), dim3(512), 0, stream, Xb, W3, bias, out);
}